// Round 10
// baseline (249.305 us; speedup 1.0000x reference)
//
#include <hip/hip_runtime.h>

// LinearAutoDecoder R10: 16-lane-group-per-row + bulk dwordx4 X staging +
// all-LDS bf16 weights + double-buffered tiles. One persistent block per CU.
//
// LDS budget (exact): W 192ch x 160dw = 122,880 B  +  X dbuf 2 x 16rows x
// 319 x 4B = 40,832 B  ->  163,712 B <= 160 KiB.
// W swizzle: dword d of channel ch stored at ch*160 + (d ^ (ch & 31)) ->
// the 4 concurrent clusters of a wave read distinct banks.
// X tile staged LINEARLY (16 rows = 20,416 B, 16B-aligned) via
// global_load_lds width-16; row alignment handled by LDS dword reads.

constexpr int POS = 63;
constexpr int LAT = 256;
constexpr int DIM = 319;
constexpr int NCH = 192;                    // 3 * 64 clusters
constexpr int WDW = 160;                    // dwords per channel (320 bf16)
constexpr int W_DWORDS = NCH * WDW;         // 30720 dw = 122,880 B
constexpr int RPT = 16;                     // rows per tile
constexpr int TILE_FLOATS = RPT * DIM;      // 5104
constexpr int TILE_F4 = TILE_FLOATS / 4;    // 1276
constexpr int NBLK = 256;                   // persistent blocks (1/CU)
constexpr size_t PW_BYTES = (size_t)W_DWORDS * 4;

// ---------- RNE float -> bf16 bits ----------
__device__ __forceinline__ unsigned f2bf(float f) {
    unsigned u = __float_as_uint(f);
    return (u + 0x7fffu + ((u >> 16) & 1u)) >> 16;
}

// ---------- pack: pw[ch*160+d] = bf16(w[ch][2d]) | bf16(w[ch][2d+1])<<16 ----
__global__ __launch_bounds__(256) void pack_weights(
    const float* __restrict__ Wp,   // [192, 63]
    const float* __restrict__ Wf,   // [192, 256]
    unsigned* __restrict__ pw)
{
    const int idx = blockIdx.x * 256 + threadIdx.x;
    if (idx >= W_DWORDS) return;
    const int ch = idx / WDW;
    const int d  = idx - ch * WDW;
    auto wat = [&](int k) -> float {
        if (k < POS) return Wp[ch * POS + k];
        if (k < DIM) return Wf[ch * LAT + (k - POS)];
        return 0.f;
    };
    pw[idx] = f2bf(wat(2 * d)) | (f2bf(wat(2 * d + 1)) << 16);
}

// ---------- 16-lane DPP reduce: lane 15 of each row-of-16 gets the sum ------
template <int CTRL>
__device__ __forceinline__ float dpp_add_step(float x) {
    int s = __builtin_amdgcn_update_dpp(0, __float_as_int(x), CTRL,
                                        0xF, 0xF, /*bound_ctrl=*/true);
    return x + __int_as_float(s);
}
__device__ __forceinline__ float group16_reduce(float x) {
    x = dpp_add_step<0x111>(x);  // row_shr:1
    x = dpp_add_step<0x112>(x);  // row_shr:2
    x = dpp_add_step<0x114>(x);  // row_shr:4
    x = dpp_add_step<0x118>(x);  // row_shr:8
    return x;                    // valid in lane 15 of each 16-lane row
}

// ---------- main: persistent, 256 thr, LDS-exact ----------
__global__ __launch_bounds__(256, 1) void lad_tile(
    const float* __restrict__ X,
    const int*   __restrict__ cid,
    const unsigned* __restrict__ pw,
    float*       __restrict__ out,
    int n)
{
    __shared__ unsigned wl[W_DWORDS];        // 122,880 B
    __shared__ float    xb[2][TILE_FLOATS];  // 2 x 20,416 B

    const int t = threadIdx.x;

    // One-time W stage: coalesced read, channel-swizzled write.
    for (int i = t; i < W_DWORDS; i += 256) {
        const int ch = i / WDW;
        const int d  = i - ch * WDW;
        wl[ch * WDW + (d ^ (ch & 31))] = pw[i];
    }

    const int ntiles = n / RPT;
    const int l   = t & 63;
    const int w   = t >> 6;
    const int g   = l >> 4;          // 16-lane group id (0..3)
    const int l16 = l & 15;
    const int rloc = w * 4 + g;      // row within tile (0..15)
    const unsigned sh = ((unsigned)((l16 & 1) ^ 1)) << 4;  // even k: <<16

    auto stage = [&](int tile, int p) {
        const char* src = (const char*)X + (size_t)tile * TILE_FLOATS * 4;
#pragma unroll
        for (int i = 0; i < 5; ++i) {
            const int slot = i * 256 + t;
            if (slot < TILE_F4) {
                __builtin_amdgcn_global_load_lds(
                    (const __attribute__((address_space(1))) unsigned int*)(src + slot * 16),
                    (__attribute__((address_space(3))) unsigned int*)&xb[p][slot * 4],
                    16, 0, 0);
            }
        }
    };

    int t0 = blockIdx.x;
    if (t0 >= ntiles) return;

    stage(t0, 0);
    int cv = cid[(size_t)t0 * RPT + rloc];   // group-uniform
    __syncthreads();                          // W staged + tile0 staged

    int p = 0;
    for (int tl = t0; tl < ntiles; tl += NBLK) {
        const int tn = tl + NBLK;
        const bool has_n = (tn < ntiles);

        if (has_n) stage(tn, p ^ 1);          // prefetch next tile

        const int ch0 = 3 * cv;
        if (has_n) cv = cid[(size_t)tn * RPT + rloc];  // prefetch next cid

        // --- compute this tile from xb[p] ---
        const float* xrow = &xb[p][rloc * DIM + l16];  // k = l16 + 16i
        // W dword index per channel: (ch0+j)*WDW + ((k>>1) ^ ((ch0+j)&31))
        const int m0 = l16 >> 1;               // k>>1 = m0 + 8i
        float a0 = 0.f, a1 = 0.f, a2 = 0.f;
#pragma unroll
        for (int i = 0; i < 20; ++i) {
            const int k = l16 + 16 * i;
            float x = xrow[16 * i];
            if (i == 19) x = (l16 < 15) ? x : 0.f;   // k == 319 mask
            const int m = m0 + 8 * i;
            const unsigned wd0 = wl[(ch0 + 0) * WDW + (m ^ ((ch0 + 0) & 31))];
            const unsigned wd1 = wl[(ch0 + 1) * WDW + (m ^ ((ch0 + 1) & 31))];
            const unsigned wd2 = wl[(ch0 + 2) * WDW + (m ^ ((ch0 + 2) & 31))];
            a0 = fmaf(x, __uint_as_float((wd0 << sh) & 0xffff0000u), a0);
            a1 = fmaf(x, __uint_as_float((wd1 << sh) & 0xffff0000u), a1);
            a2 = fmaf(x, __uint_as_float((wd2 << sh) & 0xffff0000u), a2);
        }

        a0 = group16_reduce(a0);
        a1 = group16_reduce(a1);
        a2 = group16_reduce(a2);

        if (l16 == 15) {
            float* o = out + ((size_t)tl * RPT + rloc) * 3;
            o[0] = a0; o[1] = a1; o[2] = a2;
        }

        __syncthreads();   // next tile staged; all waves done with xb[p]
        p ^= 1;
    }
}

// ---------- fallback (R2 kernel, fp32 weights): n%16 != 0 or tiny ws -------
template <int CTRL>
__device__ __forceinline__ float dpp_add_step64(float x) {
    int s = __builtin_amdgcn_update_dpp(0, __float_as_int(x), CTRL,
                                        0xF, 0xF, true);
    return x + __int_as_float(s);
}
__device__ __forceinline__ float wave_reduce_sum(float x) {
    x = dpp_add_step64<0x111>(x);
    x = dpp_add_step64<0x112>(x);
    x = dpp_add_step64<0x114>(x);
    x = dpp_add_step64<0x118>(x);
    x = dpp_add_step64<0x142>(x);  // row_bcast15
    x = dpp_add_step64<0x143>(x);  // row_bcast31
    return x;                      // lane 63
}

__global__ __launch_bounds__(256) void lad_fallback(
    const float* __restrict__ X,
    const int*   __restrict__ cid,
    const float* __restrict__ Wp,
    const float* __restrict__ Wf,
    float*       __restrict__ out,
    int n)
{
    const int lane = threadIdx.x & 63;
    const int wave = (int)((blockIdx.x * blockDim.x + threadIdx.x) >> 6);
    if (wave >= n) return;
    const size_t row = (size_t)wave;
    const float* xrow = X + row * (size_t)DIM;
    const float* xf   = xrow + POS;
    const int c3 = cid[row] * 3;
    const float* wp0 = Wp + (size_t)c3 * POS;
    const float* wf0 = Wf + (size_t)c3 * LAT;
    float a0 = 0.f, a1 = 0.f, a2 = 0.f;
#pragma unroll
    for (int i = 0; i < 4; ++i) {
        const int k = lane + 64 * i;
        const float x = xf[k];
        a0 = fmaf(x, wf0[k], a0);
        a1 = fmaf(x, wf0[k + LAT], a1);
        a2 = fmaf(x, wf0[k + 2 * LAT], a2);
    }
    if (lane < POS) {
        const float x = xrow[lane];
        a0 = fmaf(x, wp0[lane], a0);
        a1 = fmaf(x, wp0[lane + POS], a1);
        a2 = fmaf(x, wp0[lane + 2 * POS], a2);
    }
    a0 = wave_reduce_sum(a0);
    a1 = wave_reduce_sum(a1);
    a2 = wave_reduce_sum(a2);
    if (lane == 63) {
        float* o = out + row * 3;
        o[0] = a0; o[1] = a1; o[2] = a2;
    }
}

extern "C" void kernel_launch(void* const* d_in, const int* in_sizes, int n_in,
                              void* d_out, int out_size, void* d_ws, size_t ws_size,
                              hipStream_t stream) {
    const float* X   = (const float*)d_in[0];
    const int*   cid = (const int*)d_in[1];
    const float* Wp  = (const float*)d_in[2];
    const float* Wf  = (const float*)d_in[3];
    float* out = (float*)d_out;
    const int n = in_sizes[1];

    if (ws_size >= PW_BYTES && (n % RPT) == 0 && n / RPT >= 1) {
        unsigned* pw = (unsigned*)d_ws;
        pack_weights<<<(W_DWORDS + 255) / 256, 256, 0, stream>>>(Wp, Wf, pw);
        lad_tile<<<NBLK, 256, 0, stream>>>(X, cid, pw, out, n);
    } else {
        const int blocks = (n + 3) / 4;
        lad_fallback<<<blocks, 256, 0, stream>>>(X, cid, Wp, Wf, out, n);
    }
}

// Round 11
// 191.070 us; speedup vs baseline: 1.3048x; 1.3048x over previous
//
#include <hip/hip_runtime.h>

// LinearAutoDecoder R11: sequential X + bf16 register weights + 32 waves/CU +
// persistent grid-stride + depth-2 pipeline.
// R1-R10 synthesis: R8's 174us was dispatch-rate-bound (131k blocks, 0.31
// blk/cyc chip-wide); R9's 168us was latency-bound (16 waves/CU); R5's 145us
// compute had 32 waves but random X. This kernel combines the proven pieces:
// 2048 blocks (8/CU), <=64 VGPR (launch_bounds(256,8)) -> 32 waves/CU,
// chip-linear row sweep, W in 9 VGPRs (R8 bf16 pack), depth-2 prefetch of
// {X row, W dwords, cid} -> ~82KB/CU in flight >> BWxlatency requirement.

constexpr int POS = 63;
constexpr int LAT = 256;
constexpr int DIM = 319;
constexpr int NCH = 192;                       // 3 * 64 clusters
constexpr int PW_DWORDS = NCH * 192;           // 36864
constexpr size_t PW_BYTES = (size_t)PW_DWORDS * 4;
constexpr int NBLK = 2048;                     // 8 blocks/CU
constexpr int NWAVES = NBLK * 4;               // 8192 waves chip-wide

// ---------- RNE float -> bf16 bits ----------
__device__ __forceinline__ unsigned f2bf(float f) {
    unsigned u = __float_as_uint(f);
    return (u + 0x7fffu + ((u >> 16) & 1u)) >> 16;
}

// ---------- pack weights (R8 layout) ----------
// pw[ch*192 + d*64 + l] = bf16(w[ch][l+128d]) | bf16(w[ch][l+64+128d])<<16
__global__ __launch_bounds__(256) void pack_weights(
    const float* __restrict__ Wp,   // [192, 63]
    const float* __restrict__ Wf,   // [192, 256]
    unsigned* __restrict__ pw)
{
    const int idx = blockIdx.x * 256 + threadIdx.x;
    if (idx >= PW_DWORDS) return;
    const int ch  = idx / 192;
    const int rem = idx - ch * 192;
    const int d   = rem >> 6;
    const int l   = rem & 63;
    const int klo = l + 128 * d;
    const int khi = klo + 64;
    auto wat = [&](int k) -> float {
        if (k < POS) return Wp[ch * POS + k];
        if (k < DIM) return Wf[ch * LAT + (k - POS)];
        return 0.f;
    };
    pw[idx] = f2bf(wat(klo)) | (f2bf(wat(khi)) << 16);
}

// ---------- DPP wave64 sum (pure VALU), result valid in lane 63 ----------
template <int CTRL>
__device__ __forceinline__ float dpp_add_step(float x) {
    int s = __builtin_amdgcn_update_dpp(0, __float_as_int(x), CTRL,
                                        0xF, 0xF, /*bound_ctrl=*/true);
    return x + __int_as_float(s);
}
__device__ __forceinline__ float wave_reduce_sum(float x) {
    x = dpp_add_step<0x111>(x);  // row_shr:1
    x = dpp_add_step<0x112>(x);  // row_shr:2
    x = dpp_add_step<0x114>(x);  // row_shr:4
    x = dpp_add_step<0x118>(x);  // row_shr:8
    x = dpp_add_step<0x142>(x);  // row_bcast15
    x = dpp_add_step<0x143>(x);  // row_bcast31
    return x;                    // lane 63
}

__device__ __forceinline__ float blo(unsigned w) { return __uint_as_float(w << 16); }
__device__ __forceinline__ float bhi(unsigned w) { return __uint_as_float(w & 0xffff0000u); }

// ---------- main: persistent-ish grid-stride, depth-2 pipeline ----------
__global__ __launch_bounds__(256, 8) void lad_seq32(
    const float* __restrict__ X,
    const int*   __restrict__ cid,
    const unsigned* __restrict__ pw,
    float*       __restrict__ out,
    int n)
{
    const int l  = threadIdx.x & 63;
    int r = blockIdx.x * 4 + (threadIdx.x >> 6);   // chip-linear wave id
    if (r >= n) return;

    // ---- prologue: row r fully prefetched ----
    int c_cur = 3 * __builtin_amdgcn_readfirstlane(cid[r]);
    const float* xr = X + (size_t)r * DIM;
    float xa0 = xr[l];
    float xa1 = xr[l + 64];
    float xa2 = xr[l + 128];
    float xa3 = xr[l + 192];
    float xa4 = (l < 63) ? xr[l + 256] : 0.f;

    const unsigned* wb = pw + (size_t)c_cur * 192;
    unsigned wA0 = wb[l],       wA1 = wb[64 + l],  wA2 = wb[128 + l];
    unsigned wB0 = wb[192 + l], wB1 = wb[256 + l], wB2 = wb[320 + l];
    unsigned wC0 = wb[384 + l], wC1 = wb[448 + l], wC2 = wb[512 + l];

    int rn = r + NWAVES;
    int c_nxt = (rn < n) ? 3 * __builtin_amdgcn_readfirstlane(cid[rn]) : 0;

    while (true) {
        const bool has = (rn < n);

        // ---- prefetch row rn: X + W + cid(rn+NWAVES) ----
        float xb0 = 0.f, xb1 = 0.f, xb2 = 0.f, xb3 = 0.f, xb4 = 0.f;
        unsigned nA0 = 0, nA1 = 0, nA2 = 0, nB0 = 0, nB1 = 0, nB2 = 0,
                 nC0 = 0, nC1 = 0, nC2 = 0;
        int c_nn = 0;
        if (has) {
            const float* xn = X + (size_t)rn * DIM;
            xb0 = xn[l];
            xb1 = xn[l + 64];
            xb2 = xn[l + 128];
            xb3 = xn[l + 192];
            if (l < 63) xb4 = xn[l + 256];
            const unsigned* wn = pw + (size_t)c_nxt * 192;
            nA0 = wn[l];       nA1 = wn[64 + l];  nA2 = wn[128 + l];
            nB0 = wn[192 + l]; nB1 = wn[256 + l]; nB2 = wn[320 + l];
            nC0 = wn[384 + l]; nC1 = wn[448 + l]; nC2 = wn[512 + l];
            if (rn + NWAVES < n)
                c_nn = 3 * __builtin_amdgcn_readfirstlane(cid[rn + NWAVES]);
        }

        // ---- compute row r (operands prefetched last iteration) ----
        float a0 = xa0 * blo(wA0);
        a0 = fmaf(xa1, bhi(wA0), a0);
        a0 = fmaf(xa2, blo(wA1), a0);
        a0 = fmaf(xa3, bhi(wA1), a0);
        a0 = fmaf(xa4, blo(wA2), a0);

        float a1 = xa0 * blo(wB0);
        a1 = fmaf(xa1, bhi(wB0), a1);
        a1 = fmaf(xa2, blo(wB1), a1);
        a1 = fmaf(xa3, bhi(wB1), a1);
        a1 = fmaf(xa4, blo(wB2), a1);

        float a2 = xa0 * blo(wC0);
        a2 = fmaf(xa1, bhi(wC0), a2);
        a2 = fmaf(xa2, blo(wC1), a2);
        a2 = fmaf(xa3, bhi(wC1), a2);
        a2 = fmaf(xa4, blo(wC2), a2);

        a0 = wave_reduce_sum(a0);
        a1 = wave_reduce_sum(a1);
        a2 = wave_reduce_sum(a2);

        if (l == 63) {
            float* o = out + (size_t)r * 3;
            o[0] = a0; o[1] = a1; o[2] = a2;
        }

        if (!has) break;
        r = rn; rn += NWAVES;
        c_cur = c_nxt; c_nxt = c_nn;
        xa0 = xb0; xa1 = xb1; xa2 = xb2; xa3 = xb3; xa4 = xb4;
        wA0 = nA0; wA1 = nA1; wA2 = nA2;
        wB0 = nB0; wB1 = nB1; wB2 = nB2;
        wC0 = nC0; wC1 = nC1; wC2 = nC2;
    }
}

// ---------- fallback (R2 kernel, fp32 weights) if workspace too small ------
__global__ __launch_bounds__(256) void lad_fallback(
    const float* __restrict__ X,
    const int*   __restrict__ cid,
    const float* __restrict__ Wp,
    const float* __restrict__ Wf,
    float*       __restrict__ out,
    int n)
{
    const int lane = threadIdx.x & 63;
    const int wave = (int)((blockIdx.x * blockDim.x + threadIdx.x) >> 6);
    if (wave >= n) return;
    const size_t row = (size_t)wave;
    const float* xrow = X + row * (size_t)DIM;
    const float* xf   = xrow + POS;
    const int c3 = cid[row] * 3;
    const float* wp0 = Wp + (size_t)c3 * POS;
    const float* wf0 = Wf + (size_t)c3 * LAT;
    float a0 = 0.f, a1 = 0.f, a2 = 0.f;
#pragma unroll
    for (int i = 0; i < 4; ++i) {
        const int k = lane + 64 * i;
        const float x = xf[k];
        a0 = fmaf(x, wf0[k], a0);
        a1 = fmaf(x, wf0[k + LAT], a1);
        a2 = fmaf(x, wf0[k + 2 * LAT], a2);
    }
    if (lane < POS) {
        const float x = xrow[lane];
        a0 = fmaf(x, wp0[lane], a0);
        a1 = fmaf(x, wp0[lane + POS], a1);
        a2 = fmaf(x, wp0[lane + 2 * POS], a2);
    }
    a0 = wave_reduce_sum(a0);
    a1 = wave_reduce_sum(a1);
    a2 = wave_reduce_sum(a2);
    if (lane == 63) {
        float* o = out + row * 3;
        o[0] = a0; o[1] = a1; o[2] = a2;
    }
}

extern "C" void kernel_launch(void* const* d_in, const int* in_sizes, int n_in,
                              void* d_out, int out_size, void* d_ws, size_t ws_size,
                              hipStream_t stream) {
    const float* X   = (const float*)d_in[0];
    const int*   cid = (const int*)d_in[1];
    const float* Wp  = (const float*)d_in[2];
    const float* Wf  = (const float*)d_in[3];
    float* out = (float*)d_out;
    const int n = in_sizes[1];

    if (ws_size >= PW_BYTES) {
        unsigned* pw = (unsigned*)d_ws;
        pack_weights<<<(PW_DWORDS + 255) / 256, 256, 0, stream>>>(Wp, Wf, pw);
        lad_seq32<<<NBLK, 256, 0, stream>>>(X, cid, pw, out, n);
    } else {
        const int blocks = (n + 3) / 4;
        lad_fallback<<<blocks, 256, 0, stream>>>(X, cid, Wp, Wf, out, n);
    }
}